// Round 7
// baseline (10886.570 us; speedup 1.0000x reference)
//
#include <hip/hip_runtime.h>
#include <hip/hip_bf16.h>
#include <stdint.h>

#define B_   512
#define H_   1024
#define T_   144
#define NG   4096
#define NOUT 17

typedef __bf16 bf16_t;
typedef __bf16 bf16x8 __attribute__((ext_vector_type(8)));
typedef float  f32x4  __attribute__((ext_vector_type(4)));

__device__ __host__ __forceinline__ int npack(int n) {
  int g = n >> 10, j = n & 1023;
  return ((j >> 4) << 6) + (g << 4) + (j & 15);
}
__device__ __forceinline__ float sigf(float x) { return 1.f / (1.f + __expf(-x)); }
__device__ __forceinline__ float tanhf_(float x) { return 1.f - 2.f / (__expf(2.f * x) + 1.f); }

// ---------------- prep kernels (same layouts as r6) ----------------

__global__ void k_pack_wA(const float* __restrict__ Whh0, bf16_t* __restrict__ PB1) {
  int idx = blockIdx.x * 256 + threadIdx.x;     // 4096*128
  int n = idx >> 7, kc = idx & 127;
  const float* s = Whh0 + (size_t)n * H_ + kc * 8;
  bf16x8 v;
#pragma unroll
  for (int e = 0; e < 8; ++e) v[e] = (bf16_t)s[e];
  int np = npack(n), jt = np >> 6, r = np & 63;
  *(bf16x8*)(PB1 + (size_t)jt * 65536 + (kc >> 2) * 2048 + r * 32 + (kc & 3) * 8) = v;
}

__global__ void k_pack_wB(const float* __restrict__ Wih1, const float* __restrict__ Whh1,
                          bf16_t* __restrict__ PB2) {
  int idx = blockIdx.x * 256 + threadIdx.x;     // 4096*256
  int n = idx >> 8, kc = idx & 255;
  int k = kc * 8;
  const float* s = (k < H_) ? (Wih1 + (size_t)n * H_ + k) : (Whh1 + (size_t)n * H_ + (k - H_));
  bf16x8 v;
#pragma unroll
  for (int e = 0; e < 8; ++e) v[e] = (bf16_t)s[e];
  int np = npack(n), jt = np >> 6, r = np & 63;
  *(bf16x8*)(PB2 + (size_t)jt * 131072 + (kc >> 2) * 2048 + r * 32 + (kc & 3) * 8) = v;
}

__global__ void k_G(const float* __restrict__ Wih0, const float* __restrict__ ffW,
                    const float* __restrict__ ffb, float* __restrict__ G) {
  int n = blockIdx.x * 256 + threadIdx.x;       // 4096
  float acc[33];
#pragma unroll
  for (int c = 0; c < 33; ++c) acc[c] = 0.f;
  for (int k = 0; k < 512; ++k) {
    float wv = Wih0[(size_t)n * H_ + 512 + k];
    const float* fr = ffW + (size_t)k * 32;
#pragma unroll
    for (int c = 0; c < 32; ++c) acc[c] += wv * fr[c];
    acc[32] += wv * ffb[k];
  }
  for (int c = 0; c < 33; ++c) G[(size_t)c * NG + n] = acc[c];
}

__global__ void k_CHp(const float* __restrict__ cond, const float* __restrict__ G,
                      const float* __restrict__ bih0, const float* __restrict__ bhh0,
                      float* __restrict__ CHp) {
  int idx = blockIdx.x * 256 + threadIdx.x;     // 512*4096
  int b = idx >> 12, n = idx & 4095;
  float acc = bih0[n] + bhh0[n] + G[(size_t)32 * NG + n];
  const float* cb = cond + (size_t)b * 32;
#pragma unroll
  for (int c = 0; c < 32; ++c) acc += cb[c] * G[(size_t)c * NG + n];
  CHp[(size_t)b * NG + npack(n)] = acc;
}

__global__ void k_E16(const float* __restrict__ emb, const float* __restrict__ Wih0,
                      float* __restrict__ E16p) {
  int idx = blockIdx.x * 256 + threadIdx.x;     // 16*4096
  int a = idx & 15, n = idx >> 4;
  const float* er = emb + (size_t)a * 511;
  const float* wr = Wih0 + (size_t)n * H_;
  float acc = 0.f;
  for (int k = 0; k < 511; ++k) acc += er[k] * wr[k];
  E16p[(size_t)a * NG + npack(n)] = acc;
}

__global__ void k_misc(const float* __restrict__ Wih0, const float* __restrict__ bih,
                       const float* __restrict__ bhh, const float* __restrict__ fcW,
                       bf16_t* __restrict__ fcWp, float* __restrict__ biasBp,
                       float* __restrict__ wcolp) {
  int idx = blockIdx.x * 256 + threadIdx.x;     // 17408
  if (idx < NG) {
    int np = npack(idx);
    biasBp[np] = bih[NG + idx] + bhh[NG + idx];
    wcolp[np]  = Wih0[(size_t)idx * H_ + 511];
  }
  if (idx < 17 * H_) fcWp[idx] = (bf16_t)fcW[idx];
}

__global__ void k_init(const float* __restrict__ h0,
                       bf16_t* __restrict__ pah0i, bf16_t* __restrict__ pah1a) {
  int idx = blockIdx.x * 256 + threadIdx.x;     // 512*128
  int b = idx >> 7, kc = idx & 127;
  const float* s0 = h0 + (size_t)b * H_ + kc * 8;
  const float* s1 = s0 + (size_t)B_ * H_;
  bf16x8 v0, v1;
#pragma unroll
  for (int e = 0; e < 8; ++e) { v0[e] = (bf16_t)s0[e]; v1[e] = (bf16_t)s1[e]; }
  size_t po = (size_t)(kc >> 2) * 16384 + b * 32 + (kc & 3) * 8;
  *(bf16x8*)(pah0i + po) = v0;
  *(bf16x8*)(pah1a + po) = v1;
}

// ---------------- output finalization ----------------

__global__ void k_out(const float* __restrict__ preds, const float* __restrict__ fcb,
                      float* __restrict__ out) {
  int idx = blockIdx.x * 256 + threadIdx.x;     // T*B
  if (idx >= T_ * B_) return;
  int t = idx % T_, b = idx / T_;
  const float* pr = preds + ((size_t)t * B_ + b) * NOUT;
  float v[NOUT];
#pragma unroll
  for (int o = 0; o < NOUT; ++o) v[o] = pr[o] + fcb[o];
  float m = v[0];
#pragma unroll
  for (int o = 1; o < 16; ++o) m = fmaxf(m, v[o]);
  float s = 0.f;
#pragma unroll
  for (int o = 0; o < 16; ++o) s += expf(v[o] - m);
  float lse = m + logf(s);
  float* dst = out + ((size_t)b * T_ + t) * NOUT;
#pragma unroll
  for (int o = 0; o < 16; ++o) dst[o] = v[o] - lse;
  float x = v[16];
  dst[16] = (x > 0.f) ? -log1pf(expf(-x)) : (x - log1pf(expf(x)));
}

// ---------------- main persistent kernel ----------------

struct Params {
  const int* acts; const float* durs;
  const bf16_t* PB1; const bf16_t* PB2;
  const float* CHp; const float* E16p; const float* wcolp; const float* biasBp;
  const bf16_t* fcW;
  const float* c0in;
  const bf16_t* pah0i;
  bf16_t* pah0a; bf16_t* pah0b; bf16_t* pah1a; bf16_t* pah1b;
  unsigned* slots; float* preds;
};

// flag-slot grid barrier, 512 WGs: store-release own slot, poll 2 slots/thread
__device__ __forceinline__ void gbar(unsigned* slots, unsigned phase, int tid, int wg) {
  __syncthreads();
  if (tid == 0) {
    __builtin_amdgcn_fence(__ATOMIC_RELEASE, "agent");
    __hip_atomic_store(slots + (size_t)wg * 16, phase, __ATOMIC_RELAXED, __HIP_MEMORY_SCOPE_AGENT);
  }
  {
    const unsigned* a0 = slots + (size_t)tid * 16;
    const unsigned* a1 = slots + (size_t)(tid + 256) * 16;
    while (__hip_atomic_load(a0, __ATOMIC_RELAXED, __HIP_MEMORY_SCOPE_SYSTEM) < phase)
      __builtin_amdgcn_s_sleep(1);
    while (__hip_atomic_load(a1, __ATOMIC_RELAXED, __HIP_MEMORY_SCOPE_SYSTEM) < phase)
      __builtin_amdgcn_s_sleep(1);
  }
  __syncthreads();
}

// merged-block slot: h0-frag (a), h1-frag (e), W0 (b), W1ih (c), W1hh (d)
struct Slot { bf16x8 a0, e0, b0, b1, b2, b3, c0, c1, c2, c3, d0, d1, d2, d3; };

__device__ __forceinline__ void ldA1(bf16x8& r0, const char* p) {
  asm volatile("global_load_dwordx4 %0, %1, off sc0 sc1" : "=&v"(r0) : "v"(p));
}
__device__ __forceinline__ void ldA1pl(bf16x8& r0, const char* p) {
  asm volatile("global_load_dwordx4 %0, %1, off" : "=&v"(r0) : "v"(p));
}
__device__ __forceinline__ void ldB4(bf16x8& r0, bf16x8& r1, bf16x8& r2, bf16x8& r3,
                                     const char* p) {
  asm volatile("global_load_dwordx4 %0, %4, off\n\t"
               "global_load_dwordx4 %1, %4, off offset:1024\n\t"
               "global_load_dwordx4 %2, %4, off offset:2048\n\t"
               "global_load_dwordx4 %3, %4, off offset:3072"
               : "=&v"(r0), "=&v"(r1), "=&v"(r2), "=&v"(r3) : "v"(p));
}

#define VMW(N) { asm volatile("s_waitcnt vmcnt(" #N ")" ::: "memory"); \
                 __builtin_amdgcn_sched_barrier(0); }

#define MFM(ACC, AV, BV) ACC = __builtin_amdgcn_mfma_f32_16x16x32_bf16(AV, BV, ACC, 0, 0, 0)

__device__ __forceinline__ void compS(f32x4 (&A0)[4], f32x4 (&A1)[4], const Slot& S) {
  MFM(A0[0], S.a0, S.b0); MFM(A0[1], S.a0, S.b1);
  MFM(A0[2], S.a0, S.b2); MFM(A0[3], S.a0, S.b3);
  MFM(A1[0], S.a0, S.c0); MFM(A1[1], S.a0, S.c1);
  MFM(A1[2], S.a0, S.c2); MFM(A1[3], S.a0, S.c3);
  MFM(A1[0], S.e0, S.d0); MFM(A1[1], S.e0, S.d1);
  MFM(A1[2], S.e0, S.d2); MFM(A1[3], S.e0, S.d3);
}

__device__ __forceinline__ void compP(f32x4 (&A0)[4], const Slot& S) {
  MFM(A0[0], S.a0, S.b0); MFM(A0[1], S.a0, S.b1);
  MFM(A0[2], S.a0, S.b2); MFM(A0[3], S.a0, S.b3);
}

__global__ __launch_bounds__(256, 2) void lstm_main(Params p) {
  const int tid = threadIdx.x;
  const int w = tid >> 6, l = tid & 63;
  const int wg = blockIdx.x;                 // 512 WGs
  const int mt2 = (wg >> 3) & 7;             // 8 M-tiles of 64 rows
  const int jt = ((wg >> 6) << 3) | (wg & 7);// 64 jt; per XCD: 8 jt x 8 mt
  const int jj = l & 15, rq = l >> 4;
  const int jcol = jt * 16 + jj;
  const int npb = jt * 64;
  const int a_off = (mt2 * 64 + w * 16 + jj) * 64 + rq * 16;  // byte off in kk-block
  const int b_off = jj * 64 + rq * 16;
  const char* Bw0 = (const char*)p.PB1 + (size_t)jt * 131072;
  const char* Bw1 = (const char*)p.PB2 + (size_t)jt * 262144;
  const int he_off = (jcol >> 5) * 16384 + (jcol & 31);

  // fc-head rows kept in bf16 (register pressure): lane jj owns output o=jj
  bf16x8 fcw_a, fcw_b, fw16_a, fw16_b;
  {
    const char* fwp = (const char*)p.fcW;
    fcw_a  = *(const bf16x8*)(fwp + jj * 2048 + jt * 32);
    fcw_b  = *(const bf16x8*)(fwp + jj * 2048 + jt * 32 + 16);
    fw16_a = *(const bf16x8*)(fwp + 16 * 2048 + jt * 32);
    fw16_b = *(const bf16x8*)(fwp + 16 * 2048 + jt * 32 + 16);
  }

  // hoisted t-invariant per-thread state (CHp/E16p re-read per step from L2)
  float cv0[4], cv1[4], bzv[4], wcv[4];
#pragma unroll
  for (int qq = 0; qq < 4; ++qq) {
    int b = mt2 * 64 + w * 16 + rq * 4 + qq;
    cv0[qq] = p.c0in[(size_t)b * H_ + jcol];
    cv1[qq] = p.c0in[(size_t)B_ * H_ + (size_t)b * H_ + jcol];
  }
#pragma unroll
  for (int g = 0; g < 4; ++g) {
    bzv[g] = p.biasBp[npb + g * 16 + jj];
    wcv[g] = p.wcolp[npb + g * 16 + jj];
  }

  Slot S0, S1, S2;

  // ======== prologue: h0^(0) = cell0(x_0, h0_init) ========
  {
    f32x4 acc0[4];
#pragma unroll
    for (int g = 0; g < 4; ++g) acc0[g] = (f32x4){0.f, 0.f, 0.f, 0.f};

    const char* Ai = (const char*)p.pah0i;
    auto Pp = [&](int kk, Slot& S) {
      ldA1pl(S.a0, Ai + (size_t)kk * 32768 + a_off);
      ldB4(S.b0, S.b1, S.b2, S.b3, Bw0 + (size_t)kk * 4096 + b_off);
    };
    Pp(0, S0); Pp(1, S1);
#pragma unroll 1
    for (int o = 0; o < 10; ++o) {
      const int k = o * 3;
      Pp(k + 2, S2); VMW(10); compP(acc0, S0);
      Pp(k + 3, S0); VMW(10); compP(acc0, S1);
      Pp(k + 4, S1); VMW(10); compP(acc0, S2);
    }
    VMW(5);  compP(acc0, S0);
    VMW(0);  compP(acc0, S1);

    bf16_t* H0n = p.pah0a;
#pragma unroll
    for (int qq = 0; qq < 4; ++qq) {
      int b = mt2 * 64 + w * 16 + rq * 4 + qq;
      float pre[4];
#pragma unroll
      for (int g = 0; g < 4; ++g)
        pre[g] = acc0[g][qq] + p.CHp[(size_t)b * NG + npb + g * 16 + jj]
               + p.E16p[npb + g * 16 + jj];
      float cn = sigf(pre[1]) * cv0[qq] + sigf(pre[0]) * tanhf_(pre[2]);
      float hn = sigf(pre[3]) * tanhf_(cn);
      cv0[qq] = cn;
      H0n[(size_t)he_off + b * 32] = (bf16_t)hn;
    }
    gbar(p.slots, 1u, tid, wg);
  }

  // ======== main: superstep s computes h1^(s) AND h0^(s+1), one barrier ========
#pragma unroll 1
  for (int s = 0; s < T_; ++s) {
    const char* Ah0 = (const char*)((s & 1) ? p.pah0b : p.pah0a);
    bf16_t*     H0n = (s & 1) ? p.pah0a : p.pah0b;
    const char* Ah1 = (const char*)((s & 1) ? p.pah1b : p.pah1a);
    bf16_t*     H1n = (s & 1) ? p.pah1a : p.pah1b;

    f32x4 acc0[4], acc1[4];
#pragma unroll
    for (int g = 0; g < 4; ++g) {
      acc0[g] = (f32x4){0.f, 0.f, 0.f, 0.f};
      acc1[g] = (f32x4){0.f, 0.f, 0.f, 0.f};
    }

    auto Pm = [&](int kk, Slot& S) {
      ldA1(S.a0, Ah0 + (size_t)kk * 32768 + a_off);
      ldA1(S.e0, Ah1 + (size_t)kk * 32768 + a_off);
      ldB4(S.b0, S.b1, S.b2, S.b3, Bw0 + (size_t)kk * 4096 + b_off);
      ldB4(S.c0, S.c1, S.c2, S.c3, Bw1 + (size_t)kk * 4096 + b_off);
      ldB4(S.d0, S.d1, S.d2, S.d3, Bw1 + (size_t)(32 + kk) * 4096 + b_off);
    };
    Pm(0, S0); Pm(1, S1);
#pragma unroll 1
    for (int o = 0; o < 10; ++o) {
      const int k = o * 3;
      Pm(k + 2, S2); VMW(28); compS(acc0, acc1, S0);
      Pm(k + 3, S0); VMW(28); compS(acc0, acc1, S1);
      Pm(k + 4, S1); VMW(28); compS(acc0, acc1, S2);
    }
    VMW(14); compS(acc0, acc1, S0);
    VMW(0);  compS(acc0, acc1, S1);

    // epilogue: cell1 -> h1^(s) + fc head;  cell0 -> h0^(s+1)
#pragma unroll
    for (int qq = 0; qq < 4; ++qq) {
      int b = mt2 * 64 + w * 16 + rq * 4 + qq;
      // ---- layer 1 cell ----
      float pre1[4];
#pragma unroll
      for (int g = 0; g < 4; ++g) pre1[g] = acc1[g][qq] + bzv[g];
      float cn1 = sigf(pre1[1]) * cv1[qq] + sigf(pre1[0]) * tanhf_(pre1[2]);
      float hn1 = sigf(pre1[3]) * tanhf_(cn1);
      cv1[qq] = cn1;
      H1n[(size_t)he_off + b * 32] = (bf16_t)hn1;
      // fc-head partials over this WG's 16 columns
      float accO = 0.f, acc16 = 0.f;
#pragma unroll
      for (int sc = 0; sc < 8; ++sc) {
        float hs = __shfl(hn1, (l & 48) | sc, 64);
        accO  += hs * (float)fcw_a[sc];
        acc16 += hs * (float)fw16_a[sc];
      }
#pragma unroll
      for (int sc = 0; sc < 8; ++sc) {
        float hs = __shfl(hn1, (l & 48) | (8 + sc), 64);
        accO  += hs * (float)fcw_b[sc];
        acc16 += hs * (float)fw16_b[sc];
      }
      float* pb = p.preds + ((size_t)s * B_ + b) * NOUT;
      atomicAdd(pb + jj, accO);
      if (jj == 15) atomicAdd(pb + 16, acc16);
      // ---- layer 0 cell (next step's h0) ----
      int act = p.acts[(size_t)b * T_ + s];
      float dur = p.durs[(size_t)b * T_ + s];
      float pre0[4];
#pragma unroll
      for (int g = 0; g < 4; ++g)
        pre0[g] = acc0[g][qq] + p.CHp[(size_t)b * NG + npb + g * 16 + jj]
                + p.E16p[(size_t)act * NG + npb + g * 16 + jj] + dur * wcv[g];
      float cn0 = sigf(pre0[1]) * cv0[qq] + sigf(pre0[0]) * tanhf_(pre0[2]);
      float hn0 = sigf(pre0[3]) * tanhf_(cn0);
      cv0[qq] = cn0;
      H0n[(size_t)he_off + b * 32] = (bf16_t)hn0;
    }
    gbar(p.slots, (unsigned)(s + 2), tid, wg);
  }
}

// ---------------- launch ----------------

extern "C" void kernel_launch(void* const* d_in, const int* in_sizes, int n_in,
                              void* d_out, int out_size, void* d_ws, size_t ws_size,
                              hipStream_t stream) {
  (void)in_sizes; (void)n_in; (void)out_size; (void)ws_size;
  const float* h0   = (const float*)d_in[1];
  const float* c0   = (const float*)d_in[2];
  const float* cond = (const float*)d_in[3];
  const int*   acts = (const int*)d_in[4];
  const float* durs = (const float*)d_in[5];
  const float* emb  = (const float*)d_in[6];
  const float* ffW  = (const float*)d_in[7];
  const float* ffb  = (const float*)d_in[8];
  const float* Wih  = (const float*)d_in[9];
  const float* Whh  = (const float*)d_in[10];
  const float* bih  = (const float*)d_in[11];
  const float* bhh  = (const float*)d_in[12];
  const float* fcW  = (const float*)d_in[13];
  const float* fcb  = (const float*)d_in[14];

  char* ws = (char*)d_ws;
  size_t off = 0;
  auto alloc = [&](size_t bytes) -> char* {
    char* p0 = ws + off;
    off = (off + bytes + 255) & ~(size_t)255;
    return p0;
  };
  unsigned* slots = (unsigned*)alloc(512 * 64);
  bf16_t* PB1     = (bf16_t*)alloc((size_t)NG * H_ * 2);
  bf16_t* PB2     = (bf16_t*)alloc((size_t)NG * 2048 * 2);
  float*  CHp     = (float*)alloc((size_t)B_ * NG * 4);
  float*  E16p    = (float*)alloc((size_t)16 * NG * 4);
  float*  wcolp   = (float*)alloc((size_t)NG * 4);
  float*  biasBp  = (float*)alloc((size_t)NG * 4);
  float*  G       = (float*)alloc((size_t)33 * NG * 4);
  bf16_t* fcWp    = (bf16_t*)alloc((size_t)17 * H_ * 2);
  bf16_t* pah0i   = (bf16_t*)alloc((size_t)B_ * H_ * 2);
  bf16_t* pah0a   = (bf16_t*)alloc((size_t)B_ * H_ * 2);
  bf16_t* pah0b   = (bf16_t*)alloc((size_t)B_ * H_ * 2);
  bf16_t* pah1a   = (bf16_t*)alloc((size_t)B_ * H_ * 2);
  bf16_t* pah1b   = (bf16_t*)alloc((size_t)B_ * H_ * 2);
  float*  preds   = (float*)alloc((size_t)T_ * B_ * NOUT * 4);

  hipMemsetAsync(slots, 0, 512 * 64, stream);
  hipMemsetAsync(preds, 0, (size_t)T_ * B_ * NOUT * 4, stream);
  k_pack_wA<<<2048, 256, 0, stream>>>(Whh, PB1);
  k_pack_wB<<<4096, 256, 0, stream>>>(Wih + (size_t)NG * H_, Whh + (size_t)NG * H_, PB2);
  k_G<<<16, 256, 0, stream>>>(Wih, ffW, ffb, G);
  k_CHp<<<8192, 256, 0, stream>>>(cond, G, bih, bhh, CHp);
  k_E16<<<256, 256, 0, stream>>>(emb, Wih, E16p);
  k_misc<<<68, 256, 0, stream>>>(Wih, bih, bhh, fcW, fcWp, biasBp, wcolp);
  k_init<<<256, 256, 0, stream>>>(h0, pah0i, pah1a);

  Params prm;
  prm.acts = acts; prm.durs = durs;
  prm.PB1 = PB1; prm.PB2 = PB2;
  prm.CHp = CHp; prm.E16p = E16p; prm.wcolp = wcolp; prm.biasBp = biasBp;
  prm.fcW = fcWp;
  prm.c0in = c0;
  prm.pah0i = pah0i;
  prm.pah0a = pah0a; prm.pah0b = pah0b; prm.pah1a = pah1a; prm.pah1b = pah1b;
  prm.slots = slots; prm.preds = preds;

  lstm_main<<<dim3(512), dim3(256), 0, stream>>>(prm);
  k_out<<<(T_ * B_ + 255) / 256, 256, 0, stream>>>(preds, fcb, (float*)d_out);
}